// Round 10
// baseline (312.761 us; speedup 1.0000x reference)
//
#include <hip/hip_runtime.h>
#include <hip/hip_bf16.h>
#include <stdint.h>

#define NNODES 100000
#define NEDGES 1000000
#define NRELS 16
#define EPB 2048
#define NB ((NEDGES + EPB - 1) / EPB)   /* 489 */
#define BKT 256                          /* nodes per dst bucket */
#define NBKT ((NNODES + BKT - 1) / BKT)  /* 391 */
#define NTILES (NNODES / 16)             /* 6250 (exact) */

// setup grid split
#define FEAT_BLKS 6250
#define W_BLKS 256
#define SETUP_BLKS (FEAT_BLKS + W_BLKS + NB)

// ws layout (bytes):
//   featB   @ 0          : ushort[NNODES*64]      -> 12,800,000
//   Wt      @ 12800000   : ushort[16*64*64]       -> 12,931,072
//   hist391 @ 12931072   : int[NB*NBKT]           -> 13,699,072 (reserve)
//   bbase391@ 13699072   : int[NB*NBKT]           -> 14,467,072
//   bstart  @ 14467072   : int[NBKT+1]            -> 14,469,120 (reserve)
//   dnode   @ 14469120   : ushort[NEDGES]         -> 16,469,120
//   dnstart @ 16469120   : int[NBKT*256+1]        -> 16,870,016 (reserve)
//   keyE    @ 16870016   : int[NEDGES]            -> 20,870,016  src | et<<17 (bucket order)
//   keyS    @ 20870016   : int[NEDGES]            -> 24,870,016  src | et<<17 (dst-sorted)
//   tfeat   @ 24870016   : ushort[16*NNODES*64]   -> 229,670,016 (fits in 256MB L3)
#define WS_NEED 229670016ull

using short8  = __attribute__((ext_vector_type(8))) short;
using floatx4 = __attribute__((ext_vector_type(4))) float;
using uintx4  = __attribute__((ext_vector_type(4))) unsigned int;

__device__ __forceinline__ unsigned short f2bf(float f) {
    union { float f; uint32_t u; } v; v.f = f;
    uint32_t u = v.u;
    return (unsigned short)((u + 0x7FFFu + ((u >> 16) & 1u)) >> 16);
}
__device__ __forceinline__ float bf2f(uint32_t u16) {
    union { uint32_t u; float f; } v; v.u = u16 << 16;
    return v.f;
}
__device__ __forceinline__ uint32_t pk2(float a, float b) {
    __hip_bfloat162 h = __float22bfloat162_rn(make_float2(a, b));
    union { __hip_bfloat162 h; uint32_t u; } v; v.h = h;
    return v.u;
}

// fused setup: feat->bf16, W->bf16 transposed, per-block dst-bucket hist. No global atomics.
__global__ void k_setup(const float* __restrict__ feat, const float* __restrict__ W,
                        const int* __restrict__ dst,
                        unsigned short* __restrict__ featB, unsigned short* __restrict__ Wt,
                        int* __restrict__ hist391) {
    __shared__ int cnt391[NBKT];
    const int b = blockIdx.x;
    if (b < FEAT_BLKS) {
        int i = (b * 256 + threadIdx.x) * 4;
        const float4 f = *(const float4*)(feat + i);
        ushort4 o;
        o.x = f2bf(f.x); o.y = f2bf(f.y); o.z = f2bf(f.z); o.w = f2bf(f.w);
        *(ushort4*)(featB + i) = o;
    } else if (b < FEAT_BLKS + W_BLKS) {
        int t = (b - FEAT_BLKS) * 256 + threadIdx.x;   // 65536 total
        int r = t >> 12, n = (t >> 6) & 63, k = t & 63;
        Wt[t] = f2bf(W[(r << 12) + (k << 6) + n]);     // Wt[r][n][k] = W[r][k][n]
    } else {
        const int bb = b - (FEAT_BLKS + W_BLKS);
        for (int t = threadIdx.x; t < NBKT; t += 256) cnt391[t] = 0;
        __syncthreads();
        int start = bb * EPB;
        int end = min(NEDGES, start + EPB);
        for (int i = start + threadIdx.x; i < end; i += 256)
            atomicAdd(&cnt391[dst[i] >> 8], 1);
        __syncthreads();
        for (int t = threadIdx.x; t < NBKT; t += 256)
            hist391[bb * NBKT + t] = cnt391[t];
    }
}

// bucket scan A: one wave per bucket, exclusive over NB blocks; totals -> bstart[b]
__global__ void __launch_bounds__(1024)
k_bscanA(const int* __restrict__ hist391, int* __restrict__ bbase391,
         int* __restrict__ bstart) {
    int w = threadIdx.x >> 6, lane = threadIdx.x & 63;
    int b = blockIdx.x * 16 + w;
    if (b >= NBKT) return;
    int carry = 0;
    for (int c = 0; c < NB; c += 64) {
        int idx = c + lane;
        int v = (idx < NB) ? hist391[idx * NBKT + b] : 0;
        int x = v;
        #pragma unroll
        for (int off = 1; off < 64; off <<= 1) {
            int y = __shfl_up(x, off);
            if (lane >= off) x += y;
        }
        if (idx < NB) bbase391[idx * NBKT + b] = carry + x - v;
        carry += __shfl(x, 63);
    }
    if (lane == 0) bstart[b] = carry;   // totals; scanned in k_bscanB
}

// bucket scan B: parallel exclusive scan over NBKT totals (one block, 512 thr)
__global__ void k_bscanB(int* __restrict__ bstart) {
    __shared__ int wtot[8];
    int t = threadIdx.x;
    int v = (t < NBKT) ? bstart[t] : 0;
    int lane = t & 63, w = t >> 6;
    int x = v;
    #pragma unroll
    for (int off = 1; off < 64; off <<= 1) {
        int y = __shfl_up(x, off);
        if (lane >= off) x += y;
    }
    if (lane == 63) wtot[w] = x;
    __syncthreads();
    int woff = 0;
    for (int i = 0; i < w; ++i) woff += wtot[i];
    if (t < NBKT) bstart[t] = woff + x - v;
    if (t == 511) {
        int total = 0;
        for (int i = 0; i < 8; ++i) total += wtot[i];
        bstart[NBKT] = total;
    }
}

// bucket scatter: keyE[bp] = src | et<<17 at bucket position; dnode[bp] = dst&255.
// Only LDS atomics.
__global__ void k_scatter(const int* __restrict__ et, const int* __restrict__ src,
                          const int* __restrict__ dst,
                          const int* __restrict__ bbase391, const int* __restrict__ bstart,
                          int* __restrict__ keyE, unsigned short* __restrict__ dnode) {
    __shared__ int base391[NBKT];
    for (int t = threadIdx.x; t < NBKT; t += 256)
        base391[t] = bbase391[blockIdx.x * NBKT + t] + bstart[t];
    __syncthreads();
    int start = blockIdx.x * EPB;
    int end = min(NEDGES, start + EPB);
    for (int i = start + threadIdx.x; i < end; i += 256) {
        int d = dst[i];
        int bp = atomicAdd(&base391[d >> 8], 1);
        keyE[bp] = src[i] | (et[i] << 17);
        dnode[bp] = (unsigned short)(d & 255);
    }
}

// refine bucket order into full dst sort; emits final sorted keyS + per-node dnstart.
__global__ void __launch_bounds__(256)
k_bsort(const unsigned short* __restrict__ dnode, const int* __restrict__ keyE,
        const int* __restrict__ bstart,
        int* __restrict__ keyS, int* __restrict__ dnstart) {
    __shared__ int cnt[256];
    __shared__ int nodebase[256];
    __shared__ int wtot[4];
    const int b = blockIdx.x;
    const int start = bstart[b], end = bstart[b + 1];
    const int t = threadIdx.x;
    cnt[t] = 0;
    __syncthreads();
    for (int e = start + t; e < end; e += 256)
        atomicAdd(&cnt[dnode[e]], 1);
    __syncthreads();
    int v = cnt[t];
    int lane = t & 63, w = t >> 6;
    int x = v;
    #pragma unroll
    for (int off = 1; off < 64; off <<= 1) {
        int y = __shfl_up(x, off);
        if (lane >= off) x += y;
    }
    if (lane == 63) wtot[w] = x;
    __syncthreads();
    int woff = 0;
    for (int i = 0; i < w; ++i) woff += wtot[i];
    nodebase[t] = woff + x - v;          // exclusive scan
    cnt[t] = 0;
    __syncthreads();
    dnstart[b * 256 + t] = start + nodebase[t];
    if (b == NBKT - 1 && t == 255) dnstart[NBKT * 256] = end;
    for (int e = start + t; e < end; e += 256) {
        int node = dnode[e];
        int rk = atomicAdd(&cnt[node], 1);
        keyS[start + nodebase[node] + rk] = keyE[e];
    }
}

// dense transform: tfeat[r][n] = featB[n] @ W[r], all 16 relations per 16-row wave tile.
// A-frags register-resident across the relation loop; streaming full-line NT stores.
__global__ void __launch_bounds__(256)
k_tf(const unsigned short* __restrict__ featB, const unsigned short* __restrict__ Wt,
     unsigned short* __restrict__ tfeat) {
    __shared__ float lds[4][16 * 68];   // per-wave 16x64 transpose, stride 68
    const int w = threadIdx.x >> 6;
    const int tile = blockIdx.x * 4 + w;
    if (tile >= NTILES) return;
    const int base = tile * 16;
    const int lane = threadIdx.x & 63;
    const int quad = lane >> 4, l16 = lane & 15;
    const unsigned short* fp = featB + (size_t)(base + l16) * 64 + quad * 8;
    short8 a0 = *(const short8*)(fp);
    short8 a1 = *(const short8*)(fp + 32);
    const int rr = lane >> 2, seg = lane & 3;
    for (int rel = 0; rel < NRELS; ++rel) {
        const unsigned short* wr = Wt + (rel << 12);
        #pragma unroll
        for (int tn = 0; tn < 4; ++tn) {
            const unsigned short* bp = wr + ((tn * 16 + l16) << 6) + quad * 8;
            short8 b0 = *(const short8*)(bp);
            short8 b1 = *(const short8*)(bp + 32);
            floatx4 c = {0.f, 0.f, 0.f, 0.f};
            c = __builtin_amdgcn_mfma_f32_16x16x32_bf16(a0, b0, c, 0, 0, 0);
            c = __builtin_amdgcn_mfma_f32_16x16x32_bf16(a1, b1, c, 0, 0, 0);
            #pragma unroll
            for (int j = 0; j < 4; ++j)
                lds[w][(quad * 4 + j) * 68 + tn * 16 + l16] = c[j];
        }
        // lane l handles output row (l>>2), 16-col segment (l&3); rows are contiguous
        const float* lp = &lds[w][rr * 68 + seg * 16];
        uintx4 o0, o1;
        o0.x = pk2(lp[0],  lp[1]);  o0.y = pk2(lp[2],  lp[3]);
        o0.z = pk2(lp[4],  lp[5]);  o0.w = pk2(lp[6],  lp[7]);
        o1.x = pk2(lp[8],  lp[9]);  o1.y = pk2(lp[10], lp[11]);
        o1.z = pk2(lp[12], lp[13]); o1.w = pk2(lp[14], lp[15]);
        unsigned short* op = tfeat + ((size_t)rel * NNODES + base + rr) * 64 + seg * 16;
        __builtin_nontemporal_store(o0, (uintx4*)op);       // full-line sequential stream
        __builtin_nontemporal_store(o1, (uintx4*)op + 1);   // (NT ok: not scattered/partial)
    }
}

// gather-reduce: one wave per dst node; segment rows read tfeat[et][src] (L3-resident).
// 8 rows/iter: 8 lanes per row, 16 B each.
__global__ void __launch_bounds__(256)
k_gather(const unsigned short* __restrict__ tfeat, const int* __restrict__ keyS,
         const int* __restrict__ dnstart, float* __restrict__ out) {
    int n = blockIdx.x * 4 + (threadIdx.x >> 6);
    if (n >= NNODES) return;
    int lane = threadIdx.x & 63;
    int start = dnstart[n];
    int end = dnstart[n + 1];
    int c8 = (lane & 7) * 8;   // ushort col offset
    float a0 = 0.f, a1 = 0.f, a2 = 0.f, a3 = 0.f;
    float a4 = 0.f, a5 = 0.f, a6 = 0.f, a7 = 0.f;
    for (int row = start + (lane >> 3); row < end; row += 8) {
        int key = keyS[row];
        int s = key & 0x1FFFF, rel = key >> 17;
        const uintx4* p = (const uintx4*)(tfeat + ((size_t)rel * NNODES + s) * 64 + c8);
        uintx4 v = *p;
        a0 += bf2f(v.x & 0xffffu); a1 += bf2f(v.x >> 16);
        a2 += bf2f(v.y & 0xffffu); a3 += bf2f(v.y >> 16);
        a4 += bf2f(v.z & 0xffffu); a5 += bf2f(v.z >> 16);
        a6 += bf2f(v.w & 0xffffu); a7 += bf2f(v.w >> 16);
    }
    #pragma unroll
    for (int m = 8; m <= 32; m <<= 1) {
        a0 += __shfl_xor(a0, m); a1 += __shfl_xor(a1, m);
        a2 += __shfl_xor(a2, m); a3 += __shfl_xor(a3, m);
        a4 += __shfl_xor(a4, m); a5 += __shfl_xor(a5, m);
        a6 += __shfl_xor(a6, m); a7 += __shfl_xor(a7, m);
    }
    if (lane < 8) {
        float* op = out + (size_t)n * 64 + lane * 8;
        *(float4*)(op)     = make_float4(a0, a1, a2, a3);
        *(float4*)(op + 4) = make_float4(a4, a5, a6, a7);
    }
}

// Fallback (ws too small): correctness-only per-edge kernel on raw fp32 inputs.
__global__ void __launch_bounds__(256)
k_fb(const float* __restrict__ feat, const float* __restrict__ W,
     const int* __restrict__ src, const int* __restrict__ dst,
     const int* __restrict__ et, float* __restrict__ out) {
    int e = blockIdx.x * 4 + (threadIdx.x >> 6);
    if (e >= NEDGES) return;
    int c = threadIdx.x & 63;
    int s = src[e], d = dst[e], r = et[e];
    const float* fr = feat + (size_t)s * 64;
    const float* wr = W + ((size_t)r << 12);
    float acc = 0.f;
    for (int k = 0; k < 64; ++k) acc += fr[k] * wr[k * 64 + c];
    atomicAdd(out + (size_t)d * 64 + c, acc);
}

extern "C" void kernel_launch(void* const* d_in, const int* in_sizes, int n_in,
                              void* d_out, int out_size, void* d_ws, size_t ws_size,
                              hipStream_t stream) {
    const float* feat = (const float*)d_in[0];
    const float* W    = (const float*)d_in[1];
    const int* src    = (const int*)d_in[2];
    const int* dst    = (const int*)d_in[3];
    const int* et     = (const int*)d_in[4];
    float* out = (float*)d_out;
    char* ws = (char*)d_ws;

    unsigned short* featB = (unsigned short*)(ws);
    unsigned short* Wt    = (unsigned short*)(ws + 12800000);
    int* hist391  = (int*)(ws + 12931072);
    int* bbase391 = (int*)(ws + 13699072);
    int* bstart   = (int*)(ws + 14467072);
    unsigned short* dnode = (unsigned short*)(ws + 14469120);
    int* dnstart  = (int*)(ws + 16469120);
    int* keyE     = (int*)(ws + 16870016);
    int* keyS     = (int*)(ws + 20870016);
    unsigned short* tfeat = (unsigned short*)(ws + 24870016);

    if (ws_size >= WS_NEED) {
        k_setup<<<SETUP_BLKS, 256, 0, stream>>>(feat, W, dst, featB, Wt, hist391);
        k_bscanA<<<(NBKT + 15) / 16, 1024, 0, stream>>>(hist391, bbase391, bstart);
        k_bscanB<<<1, 512, 0, stream>>>(bstart);
        k_scatter<<<NB, 256, 0, stream>>>(et, src, dst, bbase391, bstart, keyE, dnode);
        k_bsort<<<NBKT, 256, 0, stream>>>(dnode, keyE, bstart, keyS, dnstart);
        k_tf<<<(NTILES + 3) / 4, 256, 0, stream>>>(featB, Wt, tfeat);
        k_gather<<<(NNODES + 3) / 4, 256, 0, stream>>>(tfeat, keyS, dnstart, out);
    } else {
        hipMemsetAsync(d_out, 0, (size_t)out_size * sizeof(float), stream);
        k_fb<<<(NEDGES + 3) / 4, 256, 0, stream>>>(feat, W, src, dst, et, out);
    }
}

// Round 11
// 235.269 us; speedup vs baseline: 1.3294x; 1.3294x over previous
//
#include <hip/hip_runtime.h>
#include <hip/hip_bf16.h>
#include <stdint.h>

#define NNODES 100000
#define NEDGES 1000000
#define NRELS 16
#define EPB 2048
#define NB ((NEDGES + EPB - 1) / EPB)   /* 489 */
#define PADCAP (NEDGES + NRELS * 64)    /* 1001024 */
#define MAXTILES (PADCAP / 64)          /* 15641 */
#define NDN NNODES
#define BKT 256
#define NBKT ((NDN + BKT - 1) / BKT)     /* 391 */

#define FEAT_BLKS 6250
#define W_BLKS 256
#define SETUP_BLKS (FEAT_BLKS + W_BLKS + NB)
#define SCANS_BLKS (1 + (NBKT + 15) / 16)

// ws layout (bytes):
//   featB   @ 0          : ushort[NNODES*64]   -> 12,800,000
//   Wt      @ 12800000   : ushort[16*64*64]    -> 12,931,072
//   hist16  @ 12931072   : int[NB*16]          -> 12,963,840
//   bbase16 @ 12963840   : int[NB*16]          -> 12,996,608
//   Pve     @ 12996608   : int[33]             -> 12,996,864
//   hist391 @ 12996864   : int[NB*NBKT]        -> 13,764,864
//   bbase391@ 13764864   : int[NB*NBKT]        -> 14,532,864
//   bstart  @ 14532864   : int[NBKT+1]         -> 14,534,912
//   dnode   @ 14534912   : ushort[NEDGES]      -> 16,534,912
//   dnstart @ 16534912   : int[NBKT*256+1]     -> 16,935,680
//   keyE    @ 16935680   : int[NEDGES]         -> 20,935,680  relpos (bucket order)
//   keyS    @ 20935680   : int[NEDGES]         -> 24,935,680  relpos (dst-sorted)
//   srcS    @ 24935680   : int[PADCAP]         -> 28,939,776  src (relation order)
//   msgE    @ 28939776   : ushort[PADCAP*64]   -> 157,070,848 (plain stores -> L3-resident)
#define WS_NEED 157070848ull

using short8  = __attribute__((ext_vector_type(8))) short;
using floatx4 = __attribute__((ext_vector_type(4))) float;
using uintx4  = __attribute__((ext_vector_type(4))) unsigned int;

__device__ __forceinline__ unsigned short f2bf(float f) {
    union { float f; uint32_t u; } v; v.f = f;
    uint32_t u = v.u;
    return (unsigned short)((u + 0x7FFFu + ((u >> 16) & 1u)) >> 16);
}
__device__ __forceinline__ float bf2f(uint32_t u16) {
    union { uint32_t u; float f; } v; v.u = u16 << 16;
    return v.f;
}
__device__ __forceinline__ uint32_t pk2(float a, float b) {
    __hip_bfloat162 h = __float22bfloat162_rn(make_float2(a, b));
    union { __hip_bfloat162 h; uint32_t u; } v; v.h = h;
    return v.u;
}

// fused setup: feat->bf16, W->bf16 transposed, per-block rel hist + dst-bucket hist.
// Plain LDS atomics only (no global atomics, no ballot loops).
__global__ void k_setup(const float* __restrict__ feat, const float* __restrict__ W,
                        const int* __restrict__ et, const int* __restrict__ dst,
                        unsigned short* __restrict__ featB, unsigned short* __restrict__ Wt,
                        int* __restrict__ hist16, int* __restrict__ hist391) {
    __shared__ int cnt16[16];
    __shared__ int cnt391[NBKT];
    const int b = blockIdx.x;
    if (b < FEAT_BLKS) {
        int i = (b * 256 + threadIdx.x) * 4;
        const float4 f = *(const float4*)(feat + i);
        ushort4 o;
        o.x = f2bf(f.x); o.y = f2bf(f.y); o.z = f2bf(f.z); o.w = f2bf(f.w);
        *(ushort4*)(featB + i) = o;
    } else if (b < FEAT_BLKS + W_BLKS) {
        int t = (b - FEAT_BLKS) * 256 + threadIdx.x;   // 65536 total
        int r = t >> 12, n = (t >> 6) & 63, k = t & 63;
        Wt[t] = f2bf(W[(r << 12) + (k << 6) + n]);     // Wt[r][n][k] = W[r][k][n]
    } else {
        const int bb = b - (FEAT_BLKS + W_BLKS);
        if (threadIdx.x < 16) cnt16[threadIdx.x] = 0;
        for (int t = threadIdx.x; t < NBKT; t += 256) cnt391[t] = 0;
        __syncthreads();
        int start = bb * EPB;
        int end = min(NEDGES, start + EPB);
        for (int i = start + threadIdx.x; i < end; i += 256) {
            atomicAdd(&cnt16[et[i]], 1);
            atomicAdd(&cnt391[dst[i] >> 8], 1);
        }
        __syncthreads();
        if (threadIdx.x < 16) hist16[bb * 16 + threadIdx.x] = cnt16[threadIdx.x];
        for (int t = threadIdx.x; t < NBKT; t += 256)
            hist391[bb * NBKT + t] = cnt391[t];
    }
}

// merged: block 0 = relation scan (16 waves, with 64-pad via Pve); blocks 1.. = bucket scanA
__global__ void __launch_bounds__(1024)
k_scans(const int* __restrict__ hist16, int* __restrict__ bbase16,
        int* __restrict__ Pve,
        const int* __restrict__ hist391, int* __restrict__ bbase391,
        int* __restrict__ bstart) {
    int w = threadIdx.x >> 6;
    int lane = threadIdx.x & 63;
    if (blockIdx.x == 0) {
        __shared__ int s_cnt[16];
        __shared__ int s_P[17];
        int carry = 0;
        for (int c = 0; c < NB; c += 64) {
            int idx = c + lane;
            int v = (idx < NB) ? hist16[idx * 16 + w] : 0;
            int x = v;
            #pragma unroll
            for (int off = 1; off < 64; off <<= 1) {
                int y = __shfl_up(x, off);
                if (lane >= off) x += y;
            }
            if (idx < NB) bbase16[idx * 16 + w] = carry + x - v;
            carry += __shfl(x, 63);
        }
        if (lane == 0) s_cnt[w] = carry;
        __syncthreads();
        if (threadIdx.x == 0) {
            int p = 0;
            for (int r = 0; r < 16; ++r) {
                s_P[r] = p;
                Pve[r] = p;
                Pve[17 + r] = p + s_cnt[r];
                p += (s_cnt[r] + 63) & ~63;
            }
            s_P[16] = p;
            Pve[16] = p;
        }
        __syncthreads();
        int pw = s_P[w];
        for (int idx = lane; idx < NB; idx += 64)
            bbase16[idx * 16 + w] += pw;
    } else {
        int b = (blockIdx.x - 1) * 16 + w;
        if (b >= NBKT) return;
        int carry = 0;
        for (int c = 0; c < NB; c += 64) {
            int idx = c + lane;
            int v = (idx < NB) ? hist391[idx * NBKT + b] : 0;
            int x = v;
            #pragma unroll
            for (int off = 1; off < 64; off <<= 1) {
                int y = __shfl_up(x, off);
                if (lane >= off) x += y;
            }
            if (idx < NB) bbase391[idx * NBKT + b] = carry + x - v;
            carry += __shfl(x, 63);
        }
        if (lane == 0) bstart[b] = carry;   // totals; scanned in k_bscanB
    }
}

// bucket scan B: parallel exclusive scan over NBKT totals (one block, 512 thr)
__global__ void k_bscanB(int* __restrict__ bstart) {
    __shared__ int wtot[8];
    int t = threadIdx.x;
    int v = (t < NBKT) ? bstart[t] : 0;
    int lane = t & 63, w = t >> 6;
    int x = v;
    #pragma unroll
    for (int off = 1; off < 64; off <<= 1) {
        int y = __shfl_up(x, off);
        if (lane >= off) x += y;
    }
    if (lane == 63) wtot[w] = x;
    __syncthreads();
    int woff = 0;
    for (int i = 0; i < w; ++i) woff += wtot[i];
    if (t < NBKT) bstart[t] = woff + x - v;
    if (t == 511) {
        int total = 0;
        for (int i = 0; i < 8; ++i) total += wtot[i];
        bstart[NBKT] = total;
    }
}

// scatter: srcS[relpos] = src; keyE[bp] = relpos; dnode[bp] = dst&255.
// All writes land at semi-sequential positions; only LDS atomics.
__global__ void k_scatter(const int* __restrict__ et, const int* __restrict__ src,
                          const int* __restrict__ dst, const int* __restrict__ bbase16,
                          const int* __restrict__ bbase391, const int* __restrict__ bstart,
                          int* __restrict__ srcS, int* __restrict__ keyE,
                          unsigned short* __restrict__ dnode) {
    __shared__ int base16[16];
    __shared__ int base391[NBKT];
    if (threadIdx.x < 16) base16[threadIdx.x] = bbase16[blockIdx.x * 16 + threadIdx.x];
    for (int t = threadIdx.x; t < NBKT; t += 256)
        base391[t] = bbase391[blockIdx.x * NBKT + t] + bstart[t];
    __syncthreads();
    int start = blockIdx.x * EPB;
    int end = min(NEDGES, start + EPB);
    for (int i = start + threadIdx.x; i < end; i += 256) {
        int r = et[i];
        int pos = atomicAdd(&base16[r], 1);
        srcS[pos] = src[i];
        int d = dst[i];
        int bp = atomicAdd(&base391[d >> 8], 1);
        keyE[bp] = pos;
        dnode[bp] = (unsigned short)(d & 255);
    }
}

// refine bucket order into full dst sort; keyS[dstpos] = relpos; dnstart per node.
__global__ void __launch_bounds__(256)
k_bsort(const unsigned short* __restrict__ dnode, const int* __restrict__ keyE,
        const int* __restrict__ bstart,
        int* __restrict__ keyS, int* __restrict__ dnstart) {
    __shared__ int cnt[256];
    __shared__ int nodebase[256];
    __shared__ int wtot[4];
    const int b = blockIdx.x;
    const int start = bstart[b], end = bstart[b + 1];
    const int t = threadIdx.x;
    cnt[t] = 0;
    __syncthreads();
    for (int e = start + t; e < end; e += 256)
        atomicAdd(&cnt[dnode[e]], 1);
    __syncthreads();
    int v = cnt[t];
    int lane = t & 63, w = t >> 6;
    int x = v;
    #pragma unroll
    for (int off = 1; off < 64; off <<= 1) {
        int y = __shfl_up(x, off);
        if (lane >= off) x += y;
    }
    if (lane == 63) wtot[w] = x;
    __syncthreads();
    int woff = 0;
    for (int i = 0; i < w; ++i) woff += wtot[i];
    nodebase[t] = woff + x - v;          // exclusive scan
    cnt[t] = 0;
    __syncthreads();
    dnstart[b * 256 + t] = start + nodebase[t];
    if (b == NBKT - 1 && t == 255) dnstart[NBKT * 256] = end;
    for (int e = start + t; e < end; e += 256) {
        int node = dnode[e];
        int rk = atomicAdd(&cnt[node], 1);
        keyS[start + nodebase[node] + rk] = keyE[e];
    }
}

// Phase A: per 64-edge tile (single relation), GEMM -> msgE row at OWN position.
// Sequential full-line PLAIN stores (keep L3-resident for the gather-reduce).
__global__ void __launch_bounds__(256)
k_computeA(const unsigned short* __restrict__ featB,
           const unsigned short* __restrict__ Wt,
           const int* __restrict__ srcS, const int* __restrict__ Pve,
           unsigned short* __restrict__ msgE) {
    __shared__ float lds[4][16 * 68];   // per-wave 16x64 transpose, stride 68
    const int w = threadIdx.x >> 6;
    const int t = blockIdx.x * 4 + w;
    const int base = t * 64;
    const int total = Pve[16];
    if (base >= total) return;
    int r = 0;
    while (base >= Pve[r + 1]) ++r;
    const int validEnd = Pve[17 + r];
    const int lane = threadIdx.x & 63;
    const int quad = lane >> 4;
    const int l16 = lane & 15;

    const unsigned short* wr = Wt + (r << 12);
    short8 bfr[4][2];
    #pragma unroll
    for (int tn = 0; tn < 4; ++tn)
        #pragma unroll
        for (int ks = 0; ks < 2; ++ks)
            bfr[tn][ks] = *(const short8*)(wr + ((tn * 16 + l16) << 6) + ks * 32 + quad * 8);

    const int rr = lane >> 2, seg = lane & 3;
    #pragma unroll
    for (int tm = 0; tm < 4; ++tm) {
        int row = base + tm * 16 + l16;
        int s = (row < validEnd) ? srcS[row] : 0;
        const unsigned short* fp = featB + (s << 6) + quad * 8;
        short8 a0 = *(const short8*)(fp);
        short8 a1 = *(const short8*)(fp + 32);
        #pragma unroll
        for (int tn = 0; tn < 4; ++tn) {
            floatx4 c = {0.f, 0.f, 0.f, 0.f};
            c = __builtin_amdgcn_mfma_f32_16x16x32_bf16(a0, bfr[tn][0], c, 0, 0, 0);
            c = __builtin_amdgcn_mfma_f32_16x16x32_bf16(a1, bfr[tn][1], c, 0, 0, 0);
            #pragma unroll
            for (int j = 0; j < 4; ++j)
                lds[w][(quad * 4 + j) * 68 + tn * 16 + l16] = c[j];
        }
        // lane l writes output row (l>>2) at its OWN global position — sequential
        int grow = base + tm * 16 + rr;
        const float* lp = &lds[w][rr * 68 + seg * 16];
        uintx4 o0, o1;
        o0.x = pk2(lp[0],  lp[1]);  o0.y = pk2(lp[2],  lp[3]);
        o0.z = pk2(lp[4],  lp[5]);  o0.w = pk2(lp[6],  lp[7]);
        o1.x = pk2(lp[8],  lp[9]);  o1.y = pk2(lp[10], lp[11]);
        o1.z = pk2(lp[12], lp[13]); o1.w = pk2(lp[14], lp[15]);
        uintx4* op = (uintx4*)(msgE + (size_t)grow * 64 + seg * 16);
        op[0] = o0;
        op[1] = o1;
    }
}

// Phase B: one wave per dst node; rows gathered via keyS (random 128B, L3-served).
// 8 rows/iter: 8 lanes per row, 16 B each.
__global__ void __launch_bounds__(256)
k_reduce(const unsigned short* __restrict__ msgE, const int* __restrict__ keyS,
         const int* __restrict__ dnstart, float* __restrict__ out) {
    int n = blockIdx.x * 4 + (threadIdx.x >> 6);
    if (n >= NDN) return;
    int lane = threadIdx.x & 63;
    int start = dnstart[n];
    int end = dnstart[n + 1];
    int c8 = (lane & 7) * 8;   // ushort col offset
    float a0 = 0.f, a1 = 0.f, a2 = 0.f, a3 = 0.f;
    float a4 = 0.f, a5 = 0.f, a6 = 0.f, a7 = 0.f;
    for (int row = start + (lane >> 3); row < end; row += 8) {
        int rp = keyS[row];
        uintx4 v = *(const uintx4*)(msgE + (size_t)rp * 64 + c8);
        a0 += bf2f(v.x & 0xffffu); a1 += bf2f(v.x >> 16);
        a2 += bf2f(v.y & 0xffffu); a3 += bf2f(v.y >> 16);
        a4 += bf2f(v.z & 0xffffu); a5 += bf2f(v.z >> 16);
        a6 += bf2f(v.w & 0xffffu); a7 += bf2f(v.w >> 16);
    }
    #pragma unroll
    for (int m = 8; m <= 32; m <<= 1) {
        a0 += __shfl_xor(a0, m); a1 += __shfl_xor(a1, m);
        a2 += __shfl_xor(a2, m); a3 += __shfl_xor(a3, m);
        a4 += __shfl_xor(a4, m); a5 += __shfl_xor(a5, m);
        a6 += __shfl_xor(a6, m); a7 += __shfl_xor(a7, m);
    }
    if (lane < 8) {
        float* op = out + (size_t)n * 64 + lane * 8;
        *(float4*)(op)     = make_float4(a0, a1, a2, a3);
        *(float4*)(op + 4) = make_float4(a4, a5, a6, a7);
    }
}

// Fallback (ws too small): correctness-only per-edge kernel on raw fp32 inputs.
__global__ void __launch_bounds__(256)
k_fb(const float* __restrict__ feat, const float* __restrict__ W,
     const int* __restrict__ src, const int* __restrict__ dst,
     const int* __restrict__ et, float* __restrict__ out) {
    int e = blockIdx.x * 4 + (threadIdx.x >> 6);
    if (e >= NEDGES) return;
    int c = threadIdx.x & 63;
    int s = src[e], d = dst[e], r = et[e];
    const float* fr = feat + (size_t)s * 64;
    const float* wr = W + ((size_t)r << 12);
    float acc = 0.f;
    for (int k = 0; k < 64; ++k) acc += fr[k] * wr[k * 64 + c];
    atomicAdd(out + (size_t)d * 64 + c, acc);
}

extern "C" void kernel_launch(void* const* d_in, const int* in_sizes, int n_in,
                              void* d_out, int out_size, void* d_ws, size_t ws_size,
                              hipStream_t stream) {
    const float* feat = (const float*)d_in[0];
    const float* W    = (const float*)d_in[1];
    const int* src    = (const int*)d_in[2];
    const int* dst    = (const int*)d_in[3];
    const int* et     = (const int*)d_in[4];
    float* out = (float*)d_out;
    char* ws = (char*)d_ws;

    unsigned short* featB = (unsigned short*)(ws);
    unsigned short* Wt    = (unsigned short*)(ws + 12800000);
    int* hist16   = (int*)(ws + 12931072);
    int* bbase16  = (int*)(ws + 12963840);
    int* Pve      = (int*)(ws + 12996608);
    int* hist391  = (int*)(ws + 12996864);
    int* bbase391 = (int*)(ws + 13764864);
    int* bstart   = (int*)(ws + 14532864);
    unsigned short* dnode = (unsigned short*)(ws + 14534912);
    int* dnstart  = (int*)(ws + 16534912);
    int* keyE     = (int*)(ws + 16935680);
    int* keyS     = (int*)(ws + 20935680);
    int* srcS     = (int*)(ws + 24935680);
    unsigned short* msgE = (unsigned short*)(ws + 28939776);

    if (ws_size >= WS_NEED) {
        k_setup<<<SETUP_BLKS, 256, 0, stream>>>(feat, W, et, dst, featB, Wt,
                                                hist16, hist391);
        k_scans<<<SCANS_BLKS, 1024, 0, stream>>>(hist16, bbase16, Pve, hist391,
                                                 bbase391, bstart);
        k_bscanB<<<1, 512, 0, stream>>>(bstart);
        k_scatter<<<NB, 256, 0, stream>>>(et, src, dst, bbase16, bbase391, bstart,
                                          srcS, keyE, dnode);
        k_bsort<<<NBKT, 256, 0, stream>>>(dnode, keyE, bstart, keyS, dnstart);
        k_computeA<<<(MAXTILES + 3) / 4, 256, 0, stream>>>(featB, Wt, srcS, Pve, msgE);
        k_reduce<<<(NDN + 3) / 4, 256, 0, stream>>>(msgE, keyS, dnstart, out);
    } else {
        hipMemsetAsync(d_out, 0, (size_t)out_size * sizeof(float), stream);
        k_fb<<<(NEDGES + 3) / 4, 256, 0, stream>>>(feat, W, src, dst, et, out);
    }
}